// Round 9
// baseline (329.974 us; speedup 1.0000x reference)
//
#include <hip/hip_runtime.h>

// VQ-VAE quantize: N=8192 rows (dim 512) vs M=8192 codes, fp32 semantics.
// k_score: 256x256 tile, 8x K=64 LDS chunks (64KB -> 2 blocks/CU), XOR-swizzle,
// bf16 MFMA screening + packed-u64 top-2; combine fused with gather; EMA+cs fused.

constexpr int N = 8192;
constexpr int K = 512;
constexpr int M = 8192;

typedef unsigned short ushortT;
typedef unsigned long long u64;
typedef __attribute__((ext_vector_type(8))) short s8v;   // 8 bf16 (4 VGPR)
typedef __attribute__((ext_vector_type(4))) float f4v;   // MFMA acc

__device__ __forceinline__ ushortT f2bf(float x) {
    unsigned u = __float_as_uint(x);
    unsigned r = (u + 0x7FFFu + ((u >> 16) & 1u)) >> 16;
    return (ushortT)r;
}
__device__ __forceinline__ float bf2f(ushortT h) {
    return __uint_as_float(((unsigned)h) << 16);
}

typedef const __attribute__((address_space(1))) unsigned gau;
typedef __attribute__((address_space(3))) unsigned lau;
__device__ __forceinline__ void gl16(const void* g, void* l) {
    __builtin_amdgcn_global_load_lds((gau*)g, (lau*)l, 16, 0, 0);
}

// sortable-float packing: enc monotone in d; low 13 bits = code index.
__device__ __forceinline__ u64 packDI(float d, int col) {
    unsigned u = __float_as_uint(d);
    unsigned e = (u & 0x80000000u) ? ~u : (u | 0x80000000u);
    return ((u64)e << 13) | (unsigned)col;
}
__device__ __forceinline__ float unpackD(u64 p) {
    unsigned e = (unsigned)(p >> 13);
    unsigned u = (e & 0x80000000u) ? (e & 0x7fffffffu) : ~e;
    return __uint_as_float(u);
}
__device__ __forceinline__ void top2u(u64& a, u64& b, u64 c) {
    u64 mn = c < a ? c : a;
    u64 mx = c < a ? a : c;
    a = mn;
    b = mx < b ? mx : b;
}

// ---------- fused prep: Fh, EhT/ElT transpose, c=||E_j||^2, zeros ----------
__global__ __launch_bounds__(256) void k_prep(
    const float* __restrict__ f, const float* __restrict__ E,
    ushortT* __restrict__ Fh, ushortT* __restrict__ EhT, ushortT* __restrict__ ElT,
    float* __restrict__ c, float* __restrict__ counts, float* __restrict__ o_diff) {
    __shared__ float tile[64][65];
    int b = blockIdx.x, t = threadIdx.x;
    if (b < 2048) {                       // prepF: f -> Fh bf16 [8192][512]
        size_t i8 = ((size_t)b * 256 + t) * 8;
        float4 x0 = *(const float4*)&f[i8];
        float4 x1 = *(const float4*)&f[i8 + 4];
        float xs[8] = {x0.x, x0.y, x0.z, x0.w, x1.x, x1.y, x1.z, x1.w};
        union { s8v v; ushortT u[8]; } h;
#pragma unroll
        for (int j = 0; j < 8; ++j) h.u[j] = f2bf(xs[j]);
        *(s8v*)&Fh[i8] = h.v;
    } else if (b < 3072) {                // prepE: E [512][8192] -> EhT,ElT [8192][512]
        int bb = b - 2048;
        int jb = bb & 127, kb = bb >> 7;
        int jj = t & 63, kk0 = t >> 6;
        int j0 = jb * 64, k0 = kb * 64;
#pragma unroll
        for (int it = 0; it < 16; ++it) {
            int kk = it * 4 + kk0;
            tile[kk][jj] = E[(size_t)(k0 + kk) * M + j0 + jj];
        }
        __syncthreads();
        int r = t >> 2, ks = (t & 3) * 16;
        union { s8v v[2]; ushortT u[16]; } h, lo;
#pragma unroll
        for (int i = 0; i < 16; ++i) {
            float x = tile[ks + i][r];
            ushortT hh = f2bf(x);
            h.u[i] = hh;
            lo.u[i] = f2bf(x - bf2f(hh));
        }
        size_t o = (size_t)(j0 + r) * K + k0 + ks;
        *(s8v*)&EhT[o] = h.v[0];
        *(s8v*)&EhT[o + 8] = h.v[1];
        *(s8v*)&ElT[o] = lo.v[0];
        *(s8v*)&ElT[o + 8] = lo.v[1];
    } else {                              // cnorm-direct + zeros (32 blocks)
        int j = (b - 3072) * 256 + t;
        float s = 0.f;
#pragma unroll 8
        for (int k = 0; k < K; ++k) {
            float e = E[(size_t)k * M + j];
            s = fmaf(e, e, s);
        }
        c[j] = s;
        counts[j] = 0.f;
        if (j == 0) o_diff[0] = 0.f;
    }
}

// ---------- main: 256x256, 8x K=64 LDS chunks, 64KB LDS (2 blocks/CU) ----------
__global__ __launch_bounds__(512) void k_score(
    const ushortT* __restrict__ Fh, const ushortT* __restrict__ Eh,
    const float* __restrict__ cE, u64* __restrict__ pv) {
    // [2 panels][256 rows][64 k] ushort = 64 KB total
    __shared__ alignas(16) ushortT ls[2 * 256 * 64];
    ushortT* lsA = ls;
    ushortT* lsB = ls + 256 * 64;

    int bid = blockIdx.x;            // 1024 blocks = 32 rb x 32 cb
    int xcd = bid & 7, local = bid >> 3;
    int rb = xcd * 4 + (local & 3);  // each XCD owns 4 row-panels (A L2-resident)
    int cb = local >> 2;             // streams B panels
    int rowBase = rb * 256, colBase = cb * 256;
    int tid = threadIdx.x;
    int w = tid >> 6, l = tid & 63;
    int wr = w >> 2, wc = w & 3;     // 2 x 4 wave grid; wave tile 128x64
    int l15 = l & 15, g4 = l >> 4;
    int s7 = l15 & 7;                // swizzle key for MFMA reads

    // staging: wave w stages rows [w*32, w*32+32) of both panels
    const ushortT* srcA = Fh + (size_t)(rowBase + w * 32) * K;
    const ushortT* srcB = Eh + (size_t)(colBase + w * 32) * K;

    f4v acc[8][4];
#pragma unroll
    for (int m = 0; m < 8; ++m)
#pragma unroll
        for (int n = 0; n < 4; ++n) acc[m][n] = (f4v){0.f, 0.f, 0.f, 0.f};

    for (int ch = 0; ch < 8; ++ch) {
        __syncthreads();   // all waves done reading previous chunk
#pragma unroll
        for (int i = 0; i < 4; ++i) {
            int q = i * 64 + l;                       // 0..255 within wave slab
            int row = q >> 3, slot = q & 7;
            int swz = (slot ^ (row & 7)) * 8;         // pre-swizzled global src slot
            size_t so = (size_t)row * K + ch * 64 + swz;
            gl16(srcA + so, &lsA[w * 2048 + q * 8]);  // linear LDS dest
            gl16(srcB + so, &lsB[w * 2048 + q * 8]);
        }
        __syncthreads();   // compiler drains vmcnt before barrier
#pragma unroll
        for (int kk = 0; kk < 2; ++kk) {
            s8v a[8], b[4];
#pragma unroll
            for (int m = 0; m < 8; ++m) {
                int rA = wr * 128 + m * 16 + l15;
                a[m] = *(const s8v*)&lsA[rA * 64 + ((kk * 4 + g4) ^ s7) * 8];
            }
#pragma unroll
            for (int n = 0; n < 4; ++n) {
                int rB = wc * 64 + n * 16 + l15;
                b[n] = *(const s8v*)&lsB[rB * 64 + ((kk * 4 + g4) ^ s7) * 8];
            }
#pragma unroll
            for (int m = 0; m < 8; ++m)
#pragma unroll
                for (int n = 0; n < 4; ++n)
                    acc[m][n] = __builtin_amdgcn_mfma_f32_16x16x32_bf16(
                        a[m], b[n], acc[m][n], 0, 0, 0);
        }
    }

    // epilogue: d = c[j] - 2*acc ; fold to 16 candidate slots per row
    float cj[4];
#pragma unroll
    for (int n = 0; n < 4; ++n) cj[n] = cE[colBase + wc * 64 + n * 16 + l15];
    __syncthreads();                       // safe to alias ls as cand
    u64* cand = (u64*)ls;                  // [256][17] u64 = 34.8 KB

#pragma unroll
    for (int m = 0; m < 8; ++m)
#pragma unroll
        for (int q = 0; q < 4; ++q) {
            u64 p0 = packDI(fmaf(-2.f, acc[m][0][q], cj[0]), colBase + wc * 64 + l15);
            u64 p1 = packDI(fmaf(-2.f, acc[m][1][q], cj[1]), colBase + wc * 64 + 16 + l15);
            u64 p2 = packDI(fmaf(-2.f, acc[m][2][q], cj[2]), colBase + wc * 64 + 32 + l15);
            u64 p3 = packDI(fmaf(-2.f, acc[m][3][q], cj[3]), colBase + wc * 64 + 48 + l15);
            u64 a_ = p0 < p1 ? p0 : p1;
            u64 b_ = p0 < p1 ? p1 : p0;
            top2u(a_, b_, p2);
            top2u(a_, b_, p3);
#pragma unroll
            for (int mk = 8; mk >= 2; mk >>= 1) {   // fold 16 lanes -> 2 (even/odd)
                u64 oa = __shfl_xor(a_, mk);
                u64 ob = __shfl_xor(b_, mk);
                top2u(a_, b_, oa);
                top2u(a_, b_, ob);
            }
            if (l15 < 2) {
                int row = wr * 128 + m * 16 + g4 * 4 + q;
                int slot = wc * 4 + l15 * 2;
                cand[row * 17 + slot] = a_;
                cand[row * 17 + slot + 1] = b_;
            }
        }
    __syncthreads();
    if (tid < 256) {
        u64 best = cand[tid * 17], second = cand[tid * 17 + 1];
#pragma unroll
        for (int i = 2; i < 16; i += 2) {
            top2u(best, second, cand[tid * 17 + i]);
            top2u(best, second, cand[tid * 17 + i + 1]);
        }
        size_t o = (size_t)(rowBase + tid) * 64 + cb * 2;   // [row][cb][2]
        pv[o] = best;
        pv[o + 1] = second;
    }
}

// ---------- combine + gather: re-rank exact, then write quantize/diff inline ----------
__global__ __launch_bounds__(256) void k_combine(
    const u64* __restrict__ pv, const float* __restrict__ f,
    const ushortT* __restrict__ EhT, const ushortT* __restrict__ ElT,
    const float* __restrict__ cE,
    int* __restrict__ indws, float* __restrict__ o_ind, float* __restrict__ counts,
    float* __restrict__ o_q, float* __restrict__ o_diff) {
    int w = threadIdx.x >> 6, l = threadIdx.x & 63;
    int row = blockIdx.x * 4 + w;
    u64 e = pv[(size_t)row * 64 + l];   // coalesced: 64 lanes x 8B contiguous
    u64 mn = e;
#pragma unroll
    for (int m = 1; m < 64; m <<= 1) {
        u64 o = __shfl_xor(mn, m);
        mn = o < mn ? o : mn;
    }
    float thr = unpackD(mn) + 1.0f;     // 14-sigma of bf16 screening error
    float dl = unpackD(e);
    float bestd = 3.4e38f; int bestj = 0x7fffffff;
    float4 fa = *(const float4*)&f[(size_t)row * K + l * 8];
    float4 fb = *(const float4*)&f[(size_t)row * K + l * 8 + 4];
    float fx[8] = {fa.x, fa.y, fa.z, fa.w, fb.x, fb.y, fb.z, fb.w};
    s8v qh, ql;                         // kept fragments of the winning code row
    unsigned long long mask = __ballot(dl <= thr);
    while (mask) {
        int b = __ffsll(mask) - 1;
        mask &= mask - 1;
        int j = (int)(__shfl(e, b) & 0x1fffu);
        s8v hv = *(const s8v*)(EhT + (size_t)j * K + l * 8);
        s8v lv = *(const s8v*)(ElT + (size_t)j * K + l * 8);
        float a = 0.f;
#pragma unroll
        for (int q = 0; q < 8; ++q)
            a = fmaf(fx[q], bf2f((ushortT)hv[q]) + bf2f((ushortT)lv[q]), a);
#pragma unroll
        for (int m = 1; m < 64; m <<= 1) a += __shfl_xor(a, m);
        float d = cE[j] - 2.f * a;
        if (d < bestd || (d == bestd && j < bestj)) {
            bestd = d; bestj = j; qh = hv; ql = lv;
        }
    }
    // fused gather: quantize_st = x + (q - x), diff += (q - x)^2
    float os[8];
    float local = 0.f;
#pragma unroll
    for (int q = 0; q < 8; ++q) {
        float qv = bf2f((ushortT)qh[q]) + bf2f((ushortT)ql[q]);
        float d = qv - fx[q];
        os[q] = fx[q] + d;
        local = fmaf(d, d, local);
    }
    float4 o0 = {os[0], os[1], os[2], os[3]};
    float4 o1 = {os[4], os[5], os[6], os[7]};
    *(float4*)&o_q[(size_t)row * K + l * 8] = o0;
    *(float4*)&o_q[(size_t)row * K + l * 8 + 4] = o1;
#pragma unroll
    for (int m = 1; m < 64; m <<= 1) local += __shfl_xor(local, m);
    if (l == 0) {
        indws[row] = bestj;
        o_ind[row] = (float)bestj;
        atomicAdd(&counts[bestj], 1.0f);
        atomicAdd(o_diff, local * (1.0f / 4194304.0f));
    }
}

// ---------- EMA (blocks 0..255) + cs (block 256) ----------
__global__ __launch_bounds__(256) void k_ema(
    const float* __restrict__ f, const int* __restrict__ indws,
    const float* __restrict__ ea, float* __restrict__ o_avg,
    const float* __restrict__ cs_in, const float* __restrict__ counts,
    float* __restrict__ o_ncs, float* __restrict__ csr) {
    int b = blockIdx.x, t = threadIdx.x;
    if (b == 256) {   // cs: new_cluster_size, n, csr
        float myncs[32];
        float loc = 0.f;
#pragma unroll 32
        for (int i = 0; i < 32; ++i) {
            int j = i * 256 + t;
            float v = 0.99f * cs_in[j] + 0.01f * counts[j];
            myncs[i] = v;
            o_ncs[j] = v;
            loc += v;
        }
#pragma unroll
        for (int off = 32; off; off >>= 1) loc += __shfl_down(loc, off);
        __shared__ float wsum[4];
        __shared__ float nsh;
        if ((t & 63) == 0) wsum[t >> 6] = loc;
        __syncthreads();
        if (t == 0) nsh = wsum[0] + wsum[1] + wsum[2] + wsum[3];
        __syncthreads();
        float n = nsh;
#pragma unroll 32
        for (int i = 0; i < 32; ++i) {
            int j = i * 256 + t;
            csr[j] = (myncs[i] + 1e-5f) / (n + 8192.0f * 1e-5f) * n;
        }
        return;
    }
    __shared__ float acc[512 * 33];   // [d][c] padded, conflict-free
    __shared__ int q[8192];
    __shared__ int qn;
    for (int i = t; i < 512 * 33; i += 256) acc[i] = 0.f;
    if (t == 0) qn = 0;
    __syncthreads();
    for (int r = t; r < N; r += 256) {
        int j = indws[r];
        if ((j >> 5) == b) {
            int s = atomicAdd(&qn, 1);
            q[s] = (r << 5) | (j & 31);
        }
    }
    __syncthreads();
    int nq = qn;
    int s = 0;
    for (; s + 4 <= nq; s += 4) {
        int e0 = q[s], e1 = q[s + 1], e2 = q[s + 2], e3 = q[s + 3];
        float a0 = f[(size_t)(e0 >> 5) * K + t],       c0 = f[(size_t)(e0 >> 5) * K + t + 256];
        float a1 = f[(size_t)(e1 >> 5) * K + t],       c1 = f[(size_t)(e1 >> 5) * K + t + 256];
        float a2 = f[(size_t)(e2 >> 5) * K + t],       c2 = f[(size_t)(e2 >> 5) * K + t + 256];
        float a3 = f[(size_t)(e3 >> 5) * K + t],       c3 = f[(size_t)(e3 >> 5) * K + t + 256];
        acc[t * 33 + (e0 & 31)] += a0;         acc[(t + 256) * 33 + (e0 & 31)] += c0;
        acc[t * 33 + (e1 & 31)] += a1;         acc[(t + 256) * 33 + (e1 & 31)] += c1;
        acc[t * 33 + (e2 & 31)] += a2;         acc[(t + 256) * 33 + (e2 & 31)] += c2;
        acc[t * 33 + (e3 & 31)] += a3;         acc[(t + 256) * 33 + (e3 & 31)] += c3;
    }
    for (; s < nq; ++s) {
        int e = q[s];
        float a0 = f[(size_t)(e >> 5) * K + t];
        float c0 = f[(size_t)(e >> 5) * K + t + 256];
        acc[t * 33 + (e & 31)] += a0;
        acc[(t + 256) * 33 + (e & 31)] += c0;
    }
    __syncthreads();
    for (int i = t; i < 512 * 32; i += 256) {
        int d = i >> 5, c = i & 31;
        size_t o = (size_t)d * M + b * 32 + c;
        o_avg[o] = 0.99f * ea[o] + 0.01f * acc[d * 33 + c];
    }
}

// ---------- new_embed = new_embed_avg / cs ----------
__global__ void k_div(const float* __restrict__ avg, const float* __restrict__ csr,
                      float* __restrict__ o_ne) {
    size_t idx = (size_t)blockIdx.x * 256 + threadIdx.x;
    size_t el = idx * 4;
    float4 a = *(const float4*)&avg[el];
    int j = (int)(el & (size_t)(M - 1));
    float4 cc = *(const float4*)&csr[j];
    float4 r;
    r.x = a.x / cc.x; r.y = a.y / cc.y; r.z = a.z / cc.z; r.w = a.w / cc.w;
    *(float4*)&o_ne[el] = r;
}

extern "C" void kernel_launch(void* const* d_in, const int* in_sizes, int n_in,
                              void* d_out, int out_size, void* d_ws, size_t ws_size,
                              hipStream_t stream) {
    const float* f     = (const float*)d_in[0];
    const float* E     = (const float*)d_in[1];
    const float* cs_in = (const float*)d_in[2];
    const float* ea    = (const float*)d_in[3];

    float* out = (float*)d_out;
    float* o_q    = out;                   // 4194304
    float* o_diff = out + 4194304;         // 1
    float* o_ind  = out + 4194305;         // 8192
    float* o_ne   = out + 4202497;         // 4194304
    float* o_ncs  = out + 8396801;         // 8192
    float* o_avg  = out + 8404993;         // 4194304

    // overlays (lifetimes audited):
    //   o_q  region: Fh (8 MB) — read by k_score only; k_combine writes o_q after
    //   o_ne region: EhT,ElT (16 MB) — read by score/combine; k_div writes last
    //   o_avg region: pv (4 MB u64) — dead after k_combine; k_ema writes o_avg after
    ushortT* Fh  = (ushortT*)o_q;
    ushortT* EhT = (ushortT*)o_ne;
    ushortT* ElT = EhT + (size_t)M * K;
    u64*     pv  = (u64*)o_avg;            // [8192 rows][32 cb][2] u64

    float* wsf    = (float*)d_ws;
    float* c      = wsf;                   // 8192
    float* counts = wsf + 8192;            // 8192
    float* csr    = wsf + 16384;           // 8192
    int*   indws  = (int*)(wsf + 24576);   // 8192

    k_prep   <<<3104, 256, 0, stream>>>(f, E, Fh, EhT, ElT, c, counts, o_diff);
    k_score  <<<1024, 512, 0, stream>>>(Fh, EhT, c, pv);
    k_combine<<<2048, 256, 0, stream>>>(pv, f, EhT, ElT, c, indws, o_ind, counts,
                                        o_q, o_diff);                 // frees Fh
    k_ema    <<<257, 256, 0, stream>>>(f, indws, ea, o_avg,
                                       cs_in, counts, o_ncs, csr);    // frees pv
    k_div    <<<4096, 256, 0, stream>>>(o_avg, csr, o_ne);            // overwrites EhT/ElT
}

// Round 10
// 278.784 us; speedup vs baseline: 1.1836x; 1.1836x over previous
//
#include <hip/hip_runtime.h>

// VQ-VAE quantize: N=8192 rows (dim 512) vs M=8192 codes, fp32 semantics.
// k_score: 256x256 tile, 8x K=64 chunks, DOUBLE-BUFFERED stage-ahead LDS
// (T3-minimum: stage ch+1 issued before compute ch, one barrier per chunk),
// XOR-swizzle, bf16 MFMA screening + packed-u32 top-2; exact fp32 re-rank.

constexpr int N = 8192;
constexpr int K = 512;
constexpr int M = 8192;

typedef unsigned short ushortT;
typedef __attribute__((ext_vector_type(8))) short s8v;   // 8 bf16 (4 VGPR)
typedef __attribute__((ext_vector_type(4))) float f4v;   // MFMA acc

__device__ __forceinline__ ushortT f2bf(float x) {
    unsigned u = __float_as_uint(x);
    unsigned r = (u + 0x7FFFu + ((u >> 16) & 1u)) >> 16;
    return (ushortT)r;
}
__device__ __forceinline__ float bf2f(ushortT h) {
    return __uint_as_float(((unsigned)h) << 16);
}

typedef const __attribute__((address_space(1))) unsigned gau;
typedef __attribute__((address_space(3))) unsigned lau;
__device__ __forceinline__ void gl16(const void* g, void* l) {
    __builtin_amdgcn_global_load_lds((gau*)g, (lau*)l, 16, 0, 0);
}

// u32 sortable-float pack: top 19 bits of sortable(d) | 13-bit col.
// Truncation understates d by <= ~1.0 at d~1e3; re-rank threshold covers it.
__device__ __forceinline__ unsigned packDI(float d, int col) {
    unsigned u = __float_as_uint(d);
    unsigned s = (u & 0x80000000u) ? ~u : (u | 0x80000000u);
    return (s & ~0x1FFFu) | (unsigned)col;
}
__device__ __forceinline__ float unpackD(unsigned p) {
    unsigned s = p & ~0x1FFFu;   // lower bound of encoded distance
    unsigned u = (s & 0x80000000u) ? (s & 0x7fffffffu) : ~s;
    return __uint_as_float(u);
}
__device__ __forceinline__ void top2u(unsigned& a, unsigned& b, unsigned c) {
    unsigned mn = c < a ? c : a;
    unsigned mx = c < a ? a : c;
    a = mn;
    b = mx < b ? mx : b;
}

// ---------- fused prep: Fh, EhT/ElT transpose, c=||E_j||^2, zeros ----------
__global__ __launch_bounds__(256) void k_prep(
    const float* __restrict__ f, const float* __restrict__ E,
    ushortT* __restrict__ Fh, ushortT* __restrict__ EhT, ushortT* __restrict__ ElT,
    float* __restrict__ c, float* __restrict__ counts, float* __restrict__ o_diff) {
    __shared__ float tile[64][65];
    int b = blockIdx.x, t = threadIdx.x;
    if (b < 2048) {                       // prepF: f -> Fh bf16 [8192][512]
        size_t i8 = ((size_t)b * 256 + t) * 8;
        float4 x0 = *(const float4*)&f[i8];
        float4 x1 = *(const float4*)&f[i8 + 4];
        float xs[8] = {x0.x, x0.y, x0.z, x0.w, x1.x, x1.y, x1.z, x1.w};
        union { s8v v; ushortT u[8]; } h;
#pragma unroll
        for (int j = 0; j < 8; ++j) h.u[j] = f2bf(xs[j]);
        *(s8v*)&Fh[i8] = h.v;
    } else if (b < 3072) {                // prepE: E [512][8192] -> EhT,ElT [8192][512]
        int bb = b - 2048;
        int jb = bb & 127, kb = bb >> 7;
        int jj = t & 63, kk0 = t >> 6;
        int j0 = jb * 64, k0 = kb * 64;
#pragma unroll
        for (int it = 0; it < 16; ++it) {
            int kk = it * 4 + kk0;
            tile[kk][jj] = E[(size_t)(k0 + kk) * M + j0 + jj];
        }
        __syncthreads();
        int r = t >> 2, ks = (t & 3) * 16;
        union { s8v v[2]; ushortT u[16]; } h, lo;
#pragma unroll
        for (int i = 0; i < 16; ++i) {
            float x = tile[ks + i][r];
            ushortT hh = f2bf(x);
            h.u[i] = hh;
            lo.u[i] = f2bf(x - bf2f(hh));
        }
        size_t o = (size_t)(j0 + r) * K + k0 + ks;
        *(s8v*)&EhT[o] = h.v[0];
        *(s8v*)&EhT[o + 8] = h.v[1];
        *(s8v*)&ElT[o] = lo.v[0];
        *(s8v*)&ElT[o + 8] = lo.v[1];
    } else {                              // cnorm-direct + zeros (32 blocks)
        int j = (b - 3072) * 256 + t;
        float s = 0.f;
#pragma unroll 8
        for (int k = 0; k < K; ++k) {
            float e = E[(size_t)k * M + j];
            s = fmaf(e, e, s);
        }
        c[j] = s;
        counts[j] = 0.f;
        if (j == 0) o_diff[0] = 0.f;
    }
}

// ---------- main: 256x256, dbuf stage-ahead K=64 chunks (128 KB LDS) ----------
__global__ __launch_bounds__(512) void k_score(
    const ushortT* __restrict__ Fh, const ushortT* __restrict__ Eh,
    const float* __restrict__ cE, unsigned* __restrict__ pv) {
    // [2 bufs][A/B][256 rows x 64 k] ushort = 128 KB
    __shared__ alignas(16) ushortT ls[2][2][256 * 64];

    int bid = blockIdx.x;            // 1024 blocks = 32 rb x 32 cb
    int xcd = bid & 7, local = bid >> 3;
    int rb = xcd * 4 + (local & 3);  // each XCD owns 4 row-panels
    int cb = local >> 2;             // streams B panels
    int rowBase = rb * 256, colBase = cb * 256;
    int tid = threadIdx.x;
    int w = tid >> 6, l = tid & 63;
    int wr = w >> 2, wc = w & 3;     // 2 x 4 wave grid; wave tile 128x64
    int l15 = l & 15, g4 = l >> 4;
    int s7 = l15 & 7;                // swizzle key for MFMA reads

    const ushortT* srcA = Fh + (size_t)(rowBase + w * 32) * K;
    const ushortT* srcB = Eh + (size_t)(colBase + w * 32) * K;

    f4v acc[8][4];
#pragma unroll
    for (int m = 0; m < 8; ++m)
#pragma unroll
        for (int n = 0; n < 4; ++n) acc[m][n] = (f4v){0.f, 0.f, 0.f, 0.f};

#define STAGE(p, ch)                                                  \
    do {                                                              \
        _Pragma("unroll")                                             \
        for (int i_ = 0; i_ < 4; ++i_) {                              \
            int q_ = i_ * 64 + l;                                     \
            int row_ = q_ >> 3, slot_ = q_ & 7;                       \
            int swz_ = (slot_ ^ (row_ & 7)) * 8;                      \
            size_t so_ = (size_t)row_ * K + (ch) * 64 + swz_;         \
            gl16(srcA + so_, &ls[p][0][w * 2048 + q_ * 8]);           \
            gl16(srcB + so_, &ls[p][1][w * 2048 + q_ * 8]);           \
        }                                                             \
    } while (0)

    STAGE(0, 0);
    __syncthreads();   // buf0 ready (compiler drains vmcnt before barrier)

    for (int ch = 0; ch < 8; ++ch) {
        int p = ch & 1;
        if (ch < 7) STAGE(p ^ 1, ch + 1);   // issue next-chunk loads FIRST
#pragma unroll
        for (int kk = 0; kk < 2; ++kk) {
            s8v a[8], b[4];
#pragma unroll
            for (int m = 0; m < 8; ++m) {
                int rA = wr * 128 + m * 16 + l15;
                a[m] = *(const s8v*)&ls[p][0][rA * 64 + ((kk * 4 + g4) ^ s7) * 8];
            }
#pragma unroll
            for (int n = 0; n < 4; ++n) {
                int rB = wc * 64 + n * 16 + l15;
                b[n] = *(const s8v*)&ls[p][1][rB * 64 + ((kk * 4 + g4) ^ s7) * 8];
            }
#pragma unroll
            for (int m = 0; m < 8; ++m)
#pragma unroll
                for (int n = 0; n < 4; ++n)
                    acc[m][n] = __builtin_amdgcn_mfma_f32_16x16x32_bf16(
                        a[m], b[n], acc[m][n], 0, 0, 0);
        }
        __syncthreads();   // stage(ch+1) drained here, AFTER compute(ch) hid it
    }
#undef STAGE

    // epilogue: d = c[j] - 2*acc ; fold to 16 u32 candidate slots per row
    float cj[4];
#pragma unroll
    for (int n = 0; n < 4; ++n) cj[n] = cE[colBase + wc * 64 + n * 16 + l15];
    unsigned* cand = (unsigned*)ls;   // aliases buf0 (last compute used buf1)

#pragma unroll
    for (int m = 0; m < 8; ++m)
#pragma unroll
        for (int q = 0; q < 4; ++q) {
            unsigned p0 = packDI(fmaf(-2.f, acc[m][0][q], cj[0]), colBase + wc * 64 + l15);
            unsigned p1 = packDI(fmaf(-2.f, acc[m][1][q], cj[1]), colBase + wc * 64 + 16 + l15);
            unsigned p2 = packDI(fmaf(-2.f, acc[m][2][q], cj[2]), colBase + wc * 64 + 32 + l15);
            unsigned p3 = packDI(fmaf(-2.f, acc[m][3][q], cj[3]), colBase + wc * 64 + 48 + l15);
            unsigned a_ = p0 < p1 ? p0 : p1;
            unsigned b_ = p0 < p1 ? p1 : p0;
            top2u(a_, b_, p2);
            top2u(a_, b_, p3);
#pragma unroll
            for (int mk = 8; mk >= 2; mk >>= 1) {   // fold 16 lanes -> 2 (even/odd)
                unsigned oa = __shfl_xor((int)a_, mk);
                unsigned ob = __shfl_xor((int)b_, mk);
                top2u(a_, b_, oa);
                top2u(a_, b_, ob);
            }
            if (l15 < 2) {
                int row = wr * 128 + m * 16 + g4 * 4 + q;
                int slot = wc * 4 + l15 * 2;
                cand[row * 17 + slot] = a_;
                cand[row * 17 + slot + 1] = b_;
            }
        }
    __syncthreads();
    if (tid < 256) {
        unsigned best = cand[tid * 17], second = cand[tid * 17 + 1];
#pragma unroll
        for (int i = 2; i < 16; i += 2) {
            top2u(best, second, cand[tid * 17 + i]);
            top2u(best, second, cand[tid * 17 + i + 1]);
        }
        size_t o = (size_t)(rowBase + tid) * 64 + cb * 2;   // [row][cb][2]
        pv[o] = best;
        pv[o + 1] = second;
    }
}

// ---------- combine + gather: exact re-rank, write quantize/diff inline ----------
__global__ __launch_bounds__(256) void k_combine(
    const unsigned* __restrict__ pv, const float* __restrict__ f,
    const ushortT* __restrict__ EhT, const ushortT* __restrict__ ElT,
    const float* __restrict__ cE,
    int* __restrict__ indws, float* __restrict__ o_ind, float* __restrict__ counts,
    float* __restrict__ o_q, float* __restrict__ o_diff) {
    int w = threadIdx.x >> 6, l = threadIdx.x & 63;
    int row = blockIdx.x * 4 + w;
    unsigned e = pv[(size_t)row * 64 + l];   // coalesced 256B per row
    unsigned mn = e;
#pragma unroll
    for (int m = 1; m < 64; m <<= 1) {
        unsigned o = __shfl_xor((int)mn, m);
        mn = o < mn ? o : mn;
    }
    // +2.0 = 1.0 pack-truncation + 1.0 (14-sigma bf16 screening error)
    float thr = unpackD(mn) + 2.0f;
    float dl = unpackD(e);
    float bestd = 3.4e38f; int bestj = 0x7fffffff;
    float4 fa = *(const float4*)&f[(size_t)row * K + l * 8];
    float4 fb = *(const float4*)&f[(size_t)row * K + l * 8 + 4];
    float fx[8] = {fa.x, fa.y, fa.z, fa.w, fb.x, fb.y, fb.z, fb.w};
    s8v qh, ql;                         // kept fragments of the winning code row
    unsigned long long mask = __ballot(dl <= thr);
    while (mask) {
        int b = __ffsll(mask) - 1;
        mask &= mask - 1;
        int j = (int)(__shfl((int)e, b) & 0x1fff);
        s8v hv = *(const s8v*)(EhT + (size_t)j * K + l * 8);
        s8v lv = *(const s8v*)(ElT + (size_t)j * K + l * 8);
        float a = 0.f;
#pragma unroll
        for (int q = 0; q < 8; ++q)
            a = fmaf(fx[q], bf2f((ushortT)hv[q]) + bf2f((ushortT)lv[q]), a);
#pragma unroll
        for (int m = 1; m < 64; m <<= 1) a += __shfl_xor(a, m);
        float d = cE[j] - 2.f * a;
        if (d < bestd || (d == bestd && j < bestj)) {
            bestd = d; bestj = j; qh = hv; ql = lv;
        }
    }
    // fused gather: quantize_st = x + (q - x), diff += (q - x)^2
    float os[8];
    float local = 0.f;
#pragma unroll
    for (int q = 0; q < 8; ++q) {
        float qv = bf2f((ushortT)qh[q]) + bf2f((ushortT)ql[q]);
        float d = qv - fx[q];
        os[q] = fx[q] + d;
        local = fmaf(d, d, local);
    }
    float4 o0 = {os[0], os[1], os[2], os[3]};
    float4 o1 = {os[4], os[5], os[6], os[7]};
    *(float4*)&o_q[(size_t)row * K + l * 8] = o0;
    *(float4*)&o_q[(size_t)row * K + l * 8 + 4] = o1;
#pragma unroll
    for (int m = 1; m < 64; m <<= 1) local += __shfl_xor(local, m);
    if (l == 0) {
        indws[row] = bestj;
        o_ind[row] = (float)bestj;
        atomicAdd(&counts[bestj], 1.0f);
        atomicAdd(o_diff, local * (1.0f / 4194304.0f));
    }
}

// ---------- EMA (blocks 0..255) + cs (block 256) ----------
__global__ __launch_bounds__(256) void k_ema(
    const float* __restrict__ f, const int* __restrict__ indws,
    const float* __restrict__ ea, float* __restrict__ o_avg,
    const float* __restrict__ cs_in, const float* __restrict__ counts,
    float* __restrict__ o_ncs, float* __restrict__ csr) {
    int b = blockIdx.x, t = threadIdx.x;
    if (b == 256) {   // cs: new_cluster_size, n, csr
        float myncs[32];
        float loc = 0.f;
#pragma unroll 32
        for (int i = 0; i < 32; ++i) {
            int j = i * 256 + t;
            float v = 0.99f * cs_in[j] + 0.01f * counts[j];
            myncs[i] = v;
            o_ncs[j] = v;
            loc += v;
        }
#pragma unroll
        for (int off = 32; off; off >>= 1) loc += __shfl_down(loc, off);
        __shared__ float wsum[4];
        __shared__ float nsh;
        if ((t & 63) == 0) wsum[t >> 6] = loc;
        __syncthreads();
        if (t == 0) nsh = wsum[0] + wsum[1] + wsum[2] + wsum[3];
        __syncthreads();
        float n = nsh;
#pragma unroll 32
        for (int i = 0; i < 32; ++i) {
            int j = i * 256 + t;
            csr[j] = (myncs[i] + 1e-5f) / (n + 8192.0f * 1e-5f) * n;
        }
        return;
    }
    __shared__ float acc[512 * 33];   // [d][c] padded, conflict-free
    __shared__ int q[8192];
    __shared__ int qn;
    for (int i = t; i < 512 * 33; i += 256) acc[i] = 0.f;
    if (t == 0) qn = 0;
    __syncthreads();
    for (int r = t; r < N; r += 256) {
        int j = indws[r];
        if ((j >> 5) == b) {
            int s = atomicAdd(&qn, 1);
            q[s] = (r << 5) | (j & 31);
        }
    }
    __syncthreads();
    int nq = qn;
    int s = 0;
    for (; s + 4 <= nq; s += 4) {
        int e0 = q[s], e1 = q[s + 1], e2 = q[s + 2], e3 = q[s + 3];
        float a0 = f[(size_t)(e0 >> 5) * K + t],       c0 = f[(size_t)(e0 >> 5) * K + t + 256];
        float a1 = f[(size_t)(e1 >> 5) * K + t],       c1 = f[(size_t)(e1 >> 5) * K + t + 256];
        float a2 = f[(size_t)(e2 >> 5) * K + t],       c2 = f[(size_t)(e2 >> 5) * K + t + 256];
        float a3 = f[(size_t)(e3 >> 5) * K + t],       c3 = f[(size_t)(e3 >> 5) * K + t + 256];
        acc[t * 33 + (e0 & 31)] += a0;         acc[(t + 256) * 33 + (e0 & 31)] += c0;
        acc[t * 33 + (e1 & 31)] += a1;         acc[(t + 256) * 33 + (e1 & 31)] += c1;
        acc[t * 33 + (e2 & 31)] += a2;         acc[(t + 256) * 33 + (e2 & 31)] += c2;
        acc[t * 33 + (e3 & 31)] += a3;         acc[(t + 256) * 33 + (e3 & 31)] += c3;
    }
    for (; s < nq; ++s) {
        int e = q[s];
        float a0 = f[(size_t)(e >> 5) * K + t];
        float c0 = f[(size_t)(e >> 5) * K + t + 256];
        acc[t * 33 + (e & 31)] += a0;
        acc[(t + 256) * 33 + (e & 31)] += c0;
    }
    __syncthreads();
    for (int i = t; i < 512 * 32; i += 256) {
        int d = i >> 5, c = i & 31;
        size_t o = (size_t)d * M + b * 32 + c;
        o_avg[o] = 0.99f * ea[o] + 0.01f * acc[d * 33 + c];
    }
}

// ---------- new_embed = new_embed_avg / cs ----------
__global__ void k_div(const float* __restrict__ avg, const float* __restrict__ csr,
                      float* __restrict__ o_ne) {
    size_t idx = (size_t)blockIdx.x * 256 + threadIdx.x;
    size_t el = idx * 4;
    float4 a = *(const float4*)&avg[el];
    int j = (int)(el & (size_t)(M - 1));
    float4 cc = *(const float4*)&csr[j];
    float4 r;
    r.x = a.x / cc.x; r.y = a.y / cc.y; r.z = a.z / cc.z; r.w = a.w / cc.w;
    *(float4*)&o_ne[el] = r;
}

extern "C" void kernel_launch(void* const* d_in, const int* in_sizes, int n_in,
                              void* d_out, int out_size, void* d_ws, size_t ws_size,
                              hipStream_t stream) {
    const float* f     = (const float*)d_in[0];
    const float* E     = (const float*)d_in[1];
    const float* cs_in = (const float*)d_in[2];
    const float* ea    = (const float*)d_in[3];

    float* out = (float*)d_out;
    float* o_q    = out;                   // 4194304
    float* o_diff = out + 4194304;         // 1
    float* o_ind  = out + 4194305;         // 8192
    float* o_ne   = out + 4202497;         // 4194304
    float* o_ncs  = out + 8396801;         // 8192
    float* o_avg  = out + 8404993;         // 4194304

    // overlays (lifetimes audited):
    //   o_q  region: Fh (8 MB) — read by k_score only; k_combine writes o_q after
    //   o_ne region: EhT,ElT (16 MB) — read by score/combine; k_div writes last
    //   o_avg region: pv (2 MB u32) — dead after k_combine; k_ema writes o_avg after
    ushortT* Fh  = (ushortT*)o_q;
    ushortT* EhT = (ushortT*)o_ne;
    ushortT* ElT = EhT + (size_t)M * K;
    unsigned* pv = (unsigned*)o_avg;       // [8192 rows][32 cb][2] u32

    float* wsf    = (float*)d_ws;
    float* c      = wsf;                   // 8192
    float* counts = wsf + 8192;            // 8192
    float* csr    = wsf + 16384;           // 8192
    int*   indws  = (int*)(wsf + 24576);   // 8192

    k_prep   <<<3104, 256, 0, stream>>>(f, E, Fh, EhT, ElT, c, counts, o_diff);
    k_score  <<<1024, 512, 0, stream>>>(Fh, EhT, c, pv);
    k_combine<<<2048, 256, 0, stream>>>(pv, f, EhT, ElT, c, indws, o_ind, counts,
                                        o_q, o_diff);                 // frees Fh
    k_ema    <<<257, 256, 0, stream>>>(f, indws, ea, o_avg,
                                       cs_in, counts, o_ncs, csr);    // frees pv
    k_div    <<<4096, 256, 0, stream>>>(o_avg, csr, o_ne);            // overwrites EhT/ElT
}

// Round 11
// 181.316 us; speedup vs baseline: 1.8199x; 1.5376x over previous
//
#include <hip/hip_runtime.h>

// VQ-VAE quantize: N=8192 rows (dim 512) vs M=8192 codes, fp32 semantics.
// k_score: 256x256 tile, dbuf stage-ahead K=64 chunks, XOR-swizzle, bf16 MFMA
// screening + packed-u32 top-2; combine: exact re-rank + fused gather, diff via
// per-block partials (no same-address atomics); privatized EMA.

constexpr int N = 8192;
constexpr int K = 512;
constexpr int M = 8192;

typedef unsigned short ushortT;
typedef __attribute__((ext_vector_type(8))) short s8v;   // 8 bf16 (4 VGPR)
typedef __attribute__((ext_vector_type(4))) float f4v;   // MFMA acc

__device__ __forceinline__ ushortT f2bf(float x) {
    unsigned u = __float_as_uint(x);
    unsigned r = (u + 0x7FFFu + ((u >> 16) & 1u)) >> 16;
    return (ushortT)r;
}
__device__ __forceinline__ float bf2f(ushortT h) {
    return __uint_as_float(((unsigned)h) << 16);
}

typedef const __attribute__((address_space(1))) unsigned gau;
typedef __attribute__((address_space(3))) unsigned lau;
__device__ __forceinline__ void gl16(const void* g, void* l) {
    __builtin_amdgcn_global_load_lds((gau*)g, (lau*)l, 16, 0, 0);
}

// u32 sortable-float pack: top 19 bits of sortable(d) | 13-bit col.
__device__ __forceinline__ unsigned packDI(float d, int col) {
    unsigned u = __float_as_uint(d);
    unsigned s = (u & 0x80000000u) ? ~u : (u | 0x80000000u);
    return (s & ~0x1FFFu) | (unsigned)col;
}
__device__ __forceinline__ float unpackD(unsigned p) {
    unsigned s = p & ~0x1FFFu;   // lower bound of encoded distance
    unsigned u = (s & 0x80000000u) ? (s & 0x7fffffffu) : ~s;
    return __uint_as_float(u);
}
__device__ __forceinline__ void top2u(unsigned& a, unsigned& b, unsigned c) {
    unsigned mn = c < a ? c : a;
    unsigned mx = c < a ? a : c;
    a = mn;
    b = mx < b ? mx : b;
}

// ---------- fused prep: Fh, EhT/ElT transpose, c=||E_j||^2, zeros ----------
__global__ __launch_bounds__(256) void k_prep(
    const float* __restrict__ f, const float* __restrict__ E,
    ushortT* __restrict__ Fh, ushortT* __restrict__ EhT, ushortT* __restrict__ ElT,
    float* __restrict__ c, float* __restrict__ counts) {
    __shared__ float tile[64][65];
    int b = blockIdx.x, t = threadIdx.x;
    if (b < 2048) {                       // prepF: f -> Fh bf16 [8192][512]
        size_t i8 = ((size_t)b * 256 + t) * 8;
        float4 x0 = *(const float4*)&f[i8];
        float4 x1 = *(const float4*)&f[i8 + 4];
        float xs[8] = {x0.x, x0.y, x0.z, x0.w, x1.x, x1.y, x1.z, x1.w};
        union { s8v v; ushortT u[8]; } h;
#pragma unroll
        for (int j = 0; j < 8; ++j) h.u[j] = f2bf(xs[j]);
        *(s8v*)&Fh[i8] = h.v;
    } else if (b < 3072) {                // prepE: E [512][8192] -> EhT,ElT [8192][512]
        int bb = b - 2048;
        int jb = bb & 127, kb = bb >> 7;
        int jj = t & 63, kk0 = t >> 6;
        int j0 = jb * 64, k0 = kb * 64;
#pragma unroll
        for (int it = 0; it < 16; ++it) {
            int kk = it * 4 + kk0;
            tile[kk][jj] = E[(size_t)(k0 + kk) * M + j0 + jj];
        }
        __syncthreads();
        int r = t >> 2, ks = (t & 3) * 16;
        union { s8v v[2]; ushortT u[16]; } h, lo;
#pragma unroll
        for (int i = 0; i < 16; ++i) {
            float x = tile[ks + i][r];
            ushortT hh = f2bf(x);
            h.u[i] = hh;
            lo.u[i] = f2bf(x - bf2f(hh));
        }
        size_t o = (size_t)(j0 + r) * K + k0 + ks;
        *(s8v*)&EhT[o] = h.v[0];
        *(s8v*)&EhT[o + 8] = h.v[1];
        *(s8v*)&ElT[o] = lo.v[0];
        *(s8v*)&ElT[o + 8] = lo.v[1];
    } else {                              // cnorm-direct + zeros (32 blocks)
        int j = (b - 3072) * 256 + t;
        float s = 0.f;
#pragma unroll 8
        for (int k = 0; k < K; ++k) {
            float e = E[(size_t)k * M + j];
            s = fmaf(e, e, s);
        }
        c[j] = s;
        counts[j] = 0.f;
    }
}

// ---------- main: 256x256, dbuf stage-ahead K=64 chunks (128 KB LDS) ----------
__global__ __launch_bounds__(512) void k_score(
    const ushortT* __restrict__ Fh, const ushortT* __restrict__ Eh,
    const float* __restrict__ cE, unsigned* __restrict__ pv) {
    // [2 bufs][A/B][256 rows x 64 k] ushort = 128 KB
    __shared__ alignas(16) ushortT ls[2][2][256 * 64];

    int bid = blockIdx.x;            // 1024 blocks = 32 rb x 32 cb
    int xcd = bid & 7, local = bid >> 3;
    int rb = xcd * 4 + (local & 3);  // each XCD owns 4 row-panels
    int cb = local >> 2;             // streams B panels
    int rowBase = rb * 256, colBase = cb * 256;
    int tid = threadIdx.x;
    int w = tid >> 6, l = tid & 63;
    int wr = w >> 2, wc = w & 3;     // 2 x 4 wave grid; wave tile 128x64
    int l15 = l & 15, g4 = l >> 4;
    int s7 = l15 & 7;                // swizzle key for MFMA reads

    const ushortT* srcA = Fh + (size_t)(rowBase + w * 32) * K;
    const ushortT* srcB = Eh + (size_t)(colBase + w * 32) * K;

    f4v acc[8][4];
#pragma unroll
    for (int m = 0; m < 8; ++m)
#pragma unroll
        for (int n = 0; n < 4; ++n) acc[m][n] = (f4v){0.f, 0.f, 0.f, 0.f};

#define STAGE(p, ch)                                                  \
    do {                                                              \
        _Pragma("unroll")                                             \
        for (int i_ = 0; i_ < 4; ++i_) {                              \
            int q_ = i_ * 64 + l;                                     \
            int row_ = q_ >> 3, slot_ = q_ & 7;                       \
            int swz_ = (slot_ ^ (row_ & 7)) * 8;                      \
            size_t so_ = (size_t)row_ * K + (ch) * 64 + swz_;         \
            gl16(srcA + so_, &ls[p][0][w * 2048 + q_ * 8]);           \
            gl16(srcB + so_, &ls[p][1][w * 2048 + q_ * 8]);           \
        }                                                             \
    } while (0)

    STAGE(0, 0);
    __syncthreads();   // buf0 ready (compiler drains vmcnt before barrier)

    for (int ch = 0; ch < 8; ++ch) {
        int p = ch & 1;
        if (ch < 7) STAGE(p ^ 1, ch + 1);   // issue next-chunk loads FIRST
#pragma unroll
        for (int kk = 0; kk < 2; ++kk) {
            s8v a[8], b[4];
#pragma unroll
            for (int m = 0; m < 8; ++m) {
                int rA = wr * 128 + m * 16 + l15;
                a[m] = *(const s8v*)&ls[p][0][rA * 64 + ((kk * 4 + g4) ^ s7) * 8];
            }
#pragma unroll
            for (int n = 0; n < 4; ++n) {
                int rB = wc * 64 + n * 16 + l15;
                b[n] = *(const s8v*)&ls[p][1][rB * 64 + ((kk * 4 + g4) ^ s7) * 8];
            }
#pragma unroll
            for (int m = 0; m < 8; ++m)
#pragma unroll
                for (int n = 0; n < 4; ++n)
                    acc[m][n] = __builtin_amdgcn_mfma_f32_16x16x32_bf16(
                        a[m], b[n], acc[m][n], 0, 0, 0);
        }
        __syncthreads();   // stage(ch+1) drained here, AFTER compute(ch) hid it
    }
#undef STAGE

    // epilogue: d = c[j] - 2*acc ; fold to 16 u32 candidate slots per row
    float cj[4];
#pragma unroll
    for (int n = 0; n < 4; ++n) cj[n] = cE[colBase + wc * 64 + n * 16 + l15];
    unsigned* cand = (unsigned*)ls;   // aliases buf0 (last compute used buf1)

#pragma unroll
    for (int m = 0; m < 8; ++m)
#pragma unroll
        for (int q = 0; q < 4; ++q) {
            unsigned p0 = packDI(fmaf(-2.f, acc[m][0][q], cj[0]), colBase + wc * 64 + l15);
            unsigned p1 = packDI(fmaf(-2.f, acc[m][1][q], cj[1]), colBase + wc * 64 + 16 + l15);
            unsigned p2 = packDI(fmaf(-2.f, acc[m][2][q], cj[2]), colBase + wc * 64 + 32 + l15);
            unsigned p3 = packDI(fmaf(-2.f, acc[m][3][q], cj[3]), colBase + wc * 64 + 48 + l15);
            unsigned a_ = p0 < p1 ? p0 : p1;
            unsigned b_ = p0 < p1 ? p1 : p0;
            top2u(a_, b_, p2);
            top2u(a_, b_, p3);
#pragma unroll
            for (int mk = 8; mk >= 2; mk >>= 1) {   // fold 16 lanes -> 2 (even/odd)
                unsigned oa = __shfl_xor((int)a_, mk);
                unsigned ob = __shfl_xor((int)b_, mk);
                top2u(a_, b_, oa);
                top2u(a_, b_, ob);
            }
            if (l15 < 2) {
                int row = wr * 128 + m * 16 + g4 * 4 + q;
                int slot = wc * 4 + l15 * 2;
                cand[row * 17 + slot] = a_;
                cand[row * 17 + slot + 1] = b_;
            }
        }
    __syncthreads();
    if (tid < 256) {
        unsigned best = cand[tid * 17], second = cand[tid * 17 + 1];
#pragma unroll
        for (int i = 2; i < 16; i += 2) {
            top2u(best, second, cand[tid * 17 + i]);
            top2u(best, second, cand[tid * 17 + i + 1]);
        }
        size_t o = (size_t)(rowBase + tid) * 64 + cb * 2;   // [row][cb][2]
        pv[o] = best;
        pv[o + 1] = second;
    }
}

// ---------- combine + gather: exact re-rank, quantize/diff; partial diff per block ----
__global__ __launch_bounds__(256) void k_combine(
    const unsigned* __restrict__ pv, const float* __restrict__ f,
    const ushortT* __restrict__ EhT, const ushortT* __restrict__ ElT,
    const float* __restrict__ cE,
    int* __restrict__ indws, float* __restrict__ o_ind, float* __restrict__ counts,
    float* __restrict__ o_q, float* __restrict__ diffp) {
    __shared__ float dsum[4];
    int w = threadIdx.x >> 6, l = threadIdx.x & 63;
    int row = blockIdx.x * 4 + w;
    unsigned e = pv[(size_t)row * 64 + l];   // coalesced 256B per row
    unsigned mn = e;
#pragma unroll
    for (int m = 1; m < 64; m <<= 1) {
        unsigned o = __shfl_xor((int)mn, m);
        mn = o < mn ? o : mn;
    }
    // +2.0 = 1.0 pack-truncation + 1.0 (14-sigma bf16 screening error)
    float thr = unpackD(mn) + 2.0f;
    float dl = unpackD(e);
    float bestd = 3.4e38f; int bestj = 0x7fffffff;
    float4 fa = *(const float4*)&f[(size_t)row * K + l * 8];
    float4 fb = *(const float4*)&f[(size_t)row * K + l * 8 + 4];
    float fx[8] = {fa.x, fa.y, fa.z, fa.w, fb.x, fb.y, fb.z, fb.w};
    s8v qh, ql;                         // kept fragments of the winning code row
    unsigned long long mask = __ballot(dl <= thr);
    while (mask) {
        int b = __ffsll(mask) - 1;
        mask &= mask - 1;
        int j = (int)(__shfl((int)e, b) & 0x1fff);
        s8v hv = *(const s8v*)(EhT + (size_t)j * K + l * 8);
        s8v lv = *(const s8v*)(ElT + (size_t)j * K + l * 8);
        float a = 0.f;
#pragma unroll
        for (int q = 0; q < 8; ++q)
            a = fmaf(fx[q], bf2f((ushortT)hv[q]) + bf2f((ushortT)lv[q]), a);
#pragma unroll
        for (int m = 1; m < 64; m <<= 1) a += __shfl_xor(a, m);
        float d = cE[j] - 2.f * a;
        if (d < bestd || (d == bestd && j < bestj)) {
            bestd = d; bestj = j; qh = hv; ql = lv;
        }
    }
    // fused gather: quantize_st = x + (q - x), diff partial = (q - x)^2
    float os[8];
    float local = 0.f;
#pragma unroll
    for (int q = 0; q < 8; ++q) {
        float qv = bf2f((ushortT)qh[q]) + bf2f((ushortT)ql[q]);
        float d = qv - fx[q];
        os[q] = fx[q] + d;
        local = fmaf(d, d, local);
    }
    float4 o0 = {os[0], os[1], os[2], os[3]};
    float4 o1 = {os[4], os[5], os[6], os[7]};
    *(float4*)&o_q[(size_t)row * K + l * 8] = o0;
    *(float4*)&o_q[(size_t)row * K + l * 8 + 4] = o1;
#pragma unroll
    for (int m = 1; m < 64; m <<= 1) local += __shfl_xor(local, m);
    if (l == 0) {
        indws[row] = bestj;
        o_ind[row] = (float)bestj;
        atomicAdd(&counts[bestj], 1.0f);   // scattered addresses: fine
        dsum[w] = local;
    }
    __syncthreads();
    if (threadIdx.x == 0)
        diffp[blockIdx.x] = dsum[0] + dsum[1] + dsum[2] + dsum[3];   // no atomic
}

// ---------- EMA (blocks 0..255) + cs & diff finalize (block 256) ----------
__global__ __launch_bounds__(256) void k_ema(
    const float* __restrict__ f, const int* __restrict__ indws,
    const float* __restrict__ ea, float* __restrict__ o_avg,
    const float* __restrict__ cs_in, const float* __restrict__ counts,
    float* __restrict__ o_ncs, float* __restrict__ csr,
    const float* __restrict__ diffp, float* __restrict__ o_diff) {
    int b = blockIdx.x, t = threadIdx.x;
    if (b == 256) {   // cs + diff finalize
        __shared__ float wsum[4];
        __shared__ float nsh;
        float myncs[32];
        float loc = 0.f;
#pragma unroll 32
        for (int i = 0; i < 32; ++i) {
            int j = i * 256 + t;
            float v = 0.99f * cs_in[j] + 0.01f * counts[j];
            myncs[i] = v;
            o_ncs[j] = v;
            loc += v;
        }
#pragma unroll
        for (int off = 32; off; off >>= 1) loc += __shfl_down(loc, off);
        if ((t & 63) == 0) wsum[t >> 6] = loc;
        __syncthreads();
        if (t == 0) nsh = wsum[0] + wsum[1] + wsum[2] + wsum[3];
        __syncthreads();
        float n = nsh;
#pragma unroll 32
        for (int i = 0; i < 32; ++i) {
            int j = i * 256 + t;
            csr[j] = (myncs[i] + 1e-5f) / (n + 8192.0f * 1e-5f) * n;
        }
        // diff = sum(diffp[0..2047]) / (N*K)
        float dl = 0.f;
#pragma unroll
        for (int i = 0; i < 8; ++i) dl += diffp[i * 256 + t];
#pragma unroll
        for (int off = 32; off; off >>= 1) dl += __shfl_down(dl, off);
        __syncthreads();
        if ((t & 63) == 0) wsum[t >> 6] = dl;
        __syncthreads();
        if (t == 0)
            o_diff[0] = (wsum[0] + wsum[1] + wsum[2] + wsum[3]) * (1.0f / 4194304.0f);
        return;
    }
    __shared__ float acc[512 * 33];   // [d][c] padded, conflict-free
    __shared__ int q[8192];
    __shared__ int qn;
    for (int i = t; i < 512 * 33; i += 256) acc[i] = 0.f;
    if (t == 0) qn = 0;
    __syncthreads();
    for (int r = t; r < N; r += 256) {
        int j = indws[r];
        if ((j >> 5) == b) {
            int s = atomicAdd(&qn, 1);
            q[s] = (r << 5) | (j & 31);
        }
    }
    __syncthreads();
    int nq = qn;
    int s = 0;
    for (; s + 4 <= nq; s += 4) {
        int e0 = q[s], e1 = q[s + 1], e2 = q[s + 2], e3 = q[s + 3];
        float a0 = f[(size_t)(e0 >> 5) * K + t],       c0 = f[(size_t)(e0 >> 5) * K + t + 256];
        float a1 = f[(size_t)(e1 >> 5) * K + t],       c1 = f[(size_t)(e1 >> 5) * K + t + 256];
        float a2 = f[(size_t)(e2 >> 5) * K + t],       c2 = f[(size_t)(e2 >> 5) * K + t + 256];
        float a3 = f[(size_t)(e3 >> 5) * K + t],       c3 = f[(size_t)(e3 >> 5) * K + t + 256];
        acc[t * 33 + (e0 & 31)] += a0;         acc[(t + 256) * 33 + (e0 & 31)] += c0;
        acc[t * 33 + (e1 & 31)] += a1;         acc[(t + 256) * 33 + (e1 & 31)] += c1;
        acc[t * 33 + (e2 & 31)] += a2;         acc[(t + 256) * 33 + (e2 & 31)] += c2;
        acc[t * 33 + (e3 & 31)] += a3;         acc[(t + 256) * 33 + (e3 & 31)] += c3;
    }
    for (; s < nq; ++s) {
        int e = q[s];
        float a0 = f[(size_t)(e >> 5) * K + t];
        float c0 = f[(size_t)(e >> 5) * K + t + 256];
        acc[t * 33 + (e & 31)] += a0;
        acc[(t + 256) * 33 + (e & 31)] += c0;
    }
    __syncthreads();
    for (int i = t; i < 512 * 32; i += 256) {
        int d = i >> 5, c = i & 31;
        size_t o = (size_t)d * M + b * 32 + c;
        o_avg[o] = 0.99f * ea[o] + 0.01f * acc[d * 33 + c];
    }
}

// ---------- new_embed = new_embed_avg / cs ----------
__global__ void k_div(const float* __restrict__ avg, const float* __restrict__ csr,
                      float* __restrict__ o_ne) {
    size_t idx = (size_t)blockIdx.x * 256 + threadIdx.x;
    size_t el = idx * 4;
    float4 a = *(const float4*)&avg[el];
    int j = (int)(el & (size_t)(M - 1));
    float4 cc = *(const float4*)&csr[j];
    float4 r;
    r.x = a.x / cc.x; r.y = a.y / cc.y; r.z = a.z / cc.z; r.w = a.w / cc.w;
    *(float4*)&o_ne[el] = r;
}

extern "C" void kernel_launch(void* const* d_in, const int* in_sizes, int n_in,
                              void* d_out, int out_size, void* d_ws, size_t ws_size,
                              hipStream_t stream) {
    const float* f     = (const float*)d_in[0];
    const float* E     = (const float*)d_in[1];
    const float* cs_in = (const float*)d_in[2];
    const float* ea    = (const float*)d_in[3];

    float* out = (float*)d_out;
    float* o_q    = out;                   // 4194304
    float* o_diff = out + 4194304;         // 1
    float* o_ind  = out + 4194305;         // 8192
    float* o_ne   = out + 4202497;         // 4194304
    float* o_ncs  = out + 8396801;         // 8192
    float* o_avg  = out + 8404993;         // 4194304

    // overlays (lifetimes audited):
    //   o_q  region: Fh (8 MB) — read by k_score only; k_combine writes o_q after
    //   o_ne region: EhT,ElT (16 MB) — read by score/combine; k_div writes last
    //   o_avg region: pv (2 MB u32) — dead after k_combine; k_ema writes o_avg after
    ushortT* Fh  = (ushortT*)o_q;
    ushortT* EhT = (ushortT*)o_ne;
    ushortT* ElT = EhT + (size_t)M * K;
    unsigned* pv = (unsigned*)o_avg;       // [8192 rows][32 cb][2] u32

    float* wsf    = (float*)d_ws;
    float* c      = wsf;                   // 8192
    float* counts = wsf + 8192;            // 8192
    float* csr    = wsf + 16384;           // 8192
    int*   indws  = (int*)(wsf + 24576);   // 8192
    float* diffp  = wsf + 32768;           // 2048 per-block diff partials

    k_prep   <<<3104, 256, 0, stream>>>(f, E, Fh, EhT, ElT, c, counts);
    k_score  <<<1024, 512, 0, stream>>>(Fh, EhT, c, pv);
    k_combine<<<2048, 256, 0, stream>>>(pv, f, EhT, ElT, c, indws, o_ind, counts,
                                        o_q, diffp);                  // frees Fh
    k_ema    <<<257, 256, 0, stream>>>(f, indws, ea, o_avg,
                                       cs_in, counts, o_ncs, csr,
                                       diffp, o_diff);                // frees pv
    k_div    <<<4096, 256, 0, stream>>>(o_avg, csr, o_ne);            // overwrites EhT/ElT
}

// Round 12
// 161.001 us; speedup vs baseline: 2.0495x; 1.1262x over previous
//
#include <hip/hip_runtime.h>

// VQ-VAE quantize: N=8192 rows (dim 512) vs M=8192 codes, fp32 semantics.
// k_score: 256x256 tile, dbuf stage-ahead K=64 chunks (fully unrolled), XOR-
// swizzle, bf16 MFMA screening + packed-u32 top-2; combine: exact re-rank +
// fused gather (block-partial diff); EMA fused with cs/div (4 launches total).

constexpr int N = 8192;
constexpr int K = 512;
constexpr int M = 8192;

typedef unsigned short ushortT;
typedef __attribute__((ext_vector_type(8))) short s8v;   // 8 bf16 (4 VGPR)
typedef __attribute__((ext_vector_type(4))) float f4v;   // MFMA acc

__device__ __forceinline__ ushortT f2bf(float x) {
    unsigned u = __float_as_uint(x);
    unsigned r = (u + 0x7FFFu + ((u >> 16) & 1u)) >> 16;
    return (ushortT)r;
}
__device__ __forceinline__ float bf2f(ushortT h) {
    return __uint_as_float(((unsigned)h) << 16);
}

typedef const __attribute__((address_space(1))) unsigned gau;
typedef __attribute__((address_space(3))) unsigned lau;
__device__ __forceinline__ void gl16(const void* g, void* l) {
    __builtin_amdgcn_global_load_lds((gau*)g, (lau*)l, 16, 0, 0);
}

// u32 sortable-float pack: top 19 bits of sortable(d) | 13-bit col.
__device__ __forceinline__ unsigned packDI(float d, int col) {
    unsigned u = __float_as_uint(d);
    unsigned s = (u & 0x80000000u) ? ~u : (u | 0x80000000u);
    return (s & ~0x1FFFu) | (unsigned)col;
}
__device__ __forceinline__ float unpackD(unsigned p) {
    unsigned s = p & ~0x1FFFu;   // lower bound of encoded distance
    unsigned u = (s & 0x80000000u) ? (s & 0x7fffffffu) : ~s;
    return __uint_as_float(u);
}
__device__ __forceinline__ void top2u(unsigned& a, unsigned& b, unsigned c) {
    unsigned mn = c < a ? c : a;
    unsigned mx = c < a ? a : c;
    a = mn;
    b = mx < b ? mx : b;
}

// ---------- fused prep: Fh; EhT/ElT transpose + pc norm partials; zero counts ----------
__global__ __launch_bounds__(256) void k_prep(
    const float* __restrict__ f, const float* __restrict__ E,
    ushortT* __restrict__ Fh, ushortT* __restrict__ EhT, ushortT* __restrict__ ElT,
    float* __restrict__ pc, float* __restrict__ counts) {
    __shared__ float tile[64][65];
    int b = blockIdx.x, t = threadIdx.x;
    if (b < 2048) {                       // prepF: f -> Fh bf16 [8192][512]
        if (b < 32) counts[b * 256 + t] = 0.f;
        size_t i8 = ((size_t)b * 256 + t) * 8;
        float4 x0 = *(const float4*)&f[i8];
        float4 x1 = *(const float4*)&f[i8 + 4];
        float xs[8] = {x0.x, x0.y, x0.z, x0.w, x1.x, x1.y, x1.z, x1.w};
        union { s8v v; ushortT u[8]; } h;
#pragma unroll
        for (int j = 0; j < 8; ++j) h.u[j] = f2bf(xs[j]);
        *(s8v*)&Fh[i8] = h.v;
    } else {                              // prepE + pc[kb][j] = partial ||E_j||^2
        int bb = b - 2048;
        int jb = bb & 127, kb = bb >> 7;
        int jj = t & 63, kk0 = t >> 6;
        int j0 = jb * 64, k0 = kb * 64;
#pragma unroll
        for (int it = 0; it < 16; ++it) {
            int kk = it * 4 + kk0;
            tile[kk][jj] = E[(size_t)(k0 + kk) * M + j0 + jj];
        }
        __syncthreads();
        int r = t >> 2, ks = (t & 3) * 16;
        union { s8v v[2]; ushortT u[16]; } h, lo;
        float nrm = 0.f;
#pragma unroll
        for (int i = 0; i < 16; ++i) {
            float x = tile[ks + i][r];
            nrm = fmaf(x, x, nrm);
            ushortT hh = f2bf(x);
            h.u[i] = hh;
            lo.u[i] = f2bf(x - bf2f(hh));
        }
        size_t o = (size_t)(j0 + r) * K + k0 + ks;
        *(s8v*)&EhT[o] = h.v[0];
        *(s8v*)&EhT[o + 8] = h.v[1];
        *(s8v*)&ElT[o] = lo.v[0];
        *(s8v*)&ElT[o + 8] = lo.v[1];
        // reduce 4 adjacent lanes (ks = 0,16,32,48) -> pc[kb][j0+r]
        nrm += __shfl_down(nrm, 2);
        nrm += __shfl_down(nrm, 1);
        if ((t & 3) == 0) pc[(size_t)kb * M + j0 + r] = nrm;
    }
}

// ---------- main: 256x256, dbuf stage-ahead K=64 chunks, fully unrolled ----------
__global__ __launch_bounds__(512) void k_score(
    const ushortT* __restrict__ Fh, const ushortT* __restrict__ Eh,
    const float* __restrict__ pc, unsigned* __restrict__ pv) {
    // [2 bufs][A/B][256 rows x 64 k] ushort = 128 KB
    __shared__ alignas(16) ushortT ls[2][2][256 * 64];

    int bid = blockIdx.x;            // 1024 blocks = 32 rb x 32 cb
    int xcd = bid & 7, local = bid >> 3;
    int rb = xcd * 4 + (local & 3);  // each XCD owns 4 row-panels
    int cb = local >> 2;             // streams B panels
    int rowBase = rb * 256, colBase = cb * 256;
    int tid = threadIdx.x;
    int w = tid >> 6, l = tid & 63;
    int wr = w >> 2, wc = w & 3;     // 2 x 4 wave grid; wave tile 128x64
    int l15 = l & 15, g4 = l >> 4;
    int s7 = l15 & 7;                // swizzle key for MFMA reads

    const ushortT* srcA = Fh + (size_t)(rowBase + w * 32) * K;
    const ushortT* srcB = Eh + (size_t)(colBase + w * 32) * K;

    f4v acc[8][4];
#pragma unroll
    for (int m = 0; m < 8; ++m)
#pragma unroll
        for (int n = 0; n < 4; ++n) acc[m][n] = (f4v){0.f, 0.f, 0.f, 0.f};

#define STAGE(p, ch)                                                  \
    do {                                                              \
        _Pragma("unroll")                                             \
        for (int i_ = 0; i_ < 4; ++i_) {                              \
            int q_ = i_ * 64 + l;                                     \
            int row_ = q_ >> 3, slot_ = q_ & 7;                       \
            int swz_ = (slot_ ^ (row_ & 7)) * 8;                      \
            size_t so_ = (size_t)row_ * K + (ch) * 64 + swz_;         \
            gl16(srcA + so_, &ls[p][0][w * 2048 + q_ * 8]);           \
            gl16(srcB + so_, &ls[p][1][w * 2048 + q_ * 8]);           \
        }                                                             \
    } while (0)

    STAGE(0, 0);
    __syncthreads();   // buf0 ready (compiler drains vmcnt before barrier)

#pragma unroll
    for (int ch = 0; ch < 8; ++ch) {   // FULL UNROLL: addresses fold to imm offsets
        int p = ch & 1;
        if (ch < 7) STAGE(p ^ 1, ch + 1);   // issue next-chunk loads FIRST
#pragma unroll
        for (int kk = 0; kk < 2; ++kk) {
            s8v a[8], b[4];
#pragma unroll
            for (int m = 0; m < 8; ++m) {
                int rA = wr * 128 + m * 16 + l15;
                a[m] = *(const s8v*)&ls[p][0][rA * 64 + ((kk * 4 + g4) ^ s7) * 8];
            }
#pragma unroll
            for (int n = 0; n < 4; ++n) {
                int rB = wc * 64 + n * 16 + l15;
                b[n] = *(const s8v*)&ls[p][1][rB * 64 + ((kk * 4 + g4) ^ s7) * 8];
            }
#pragma unroll
            for (int m = 0; m < 8; ++m)
#pragma unroll
                for (int n = 0; n < 4; ++n)
                    acc[m][n] = __builtin_amdgcn_mfma_f32_16x16x32_bf16(
                        a[m], b[n], acc[m][n], 0, 0, 0);
        }
        __syncthreads();   // stage(ch+1) drained here, AFTER compute(ch) hid it
    }
#undef STAGE

    // epilogue: cj = sum of 8 norm partials; d = cj - 2*acc; fold to 16 slots/row
    float cj[4];
#pragma unroll
    for (int n = 0; n < 4; ++n) {
        int col = colBase + wc * 64 + n * 16 + l15;
        float s = 0.f;
#pragma unroll
        for (int kb = 0; kb < 8; ++kb) s += pc[(size_t)kb * M + col];
        cj[n] = s;
    }
    unsigned* cand = (unsigned*)ls;   // aliases buf0 (last compute used buf1)

#pragma unroll
    for (int m = 0; m < 8; ++m)
#pragma unroll
        for (int q = 0; q < 4; ++q) {
            unsigned p0 = packDI(fmaf(-2.f, acc[m][0][q], cj[0]), colBase + wc * 64 + l15);
            unsigned p1 = packDI(fmaf(-2.f, acc[m][1][q], cj[1]), colBase + wc * 64 + 16 + l15);
            unsigned p2 = packDI(fmaf(-2.f, acc[m][2][q], cj[2]), colBase + wc * 64 + 32 + l15);
            unsigned p3 = packDI(fmaf(-2.f, acc[m][3][q], cj[3]), colBase + wc * 64 + 48 + l15);
            unsigned a_ = p0 < p1 ? p0 : p1;
            unsigned b_ = p0 < p1 ? p1 : p0;
            top2u(a_, b_, p2);
            top2u(a_, b_, p3);
#pragma unroll
            for (int mk = 8; mk >= 2; mk >>= 1) {   // fold 16 lanes -> 2 (even/odd)
                unsigned oa = __shfl_xor((int)a_, mk);
                unsigned ob = __shfl_xor((int)b_, mk);
                top2u(a_, b_, oa);
                top2u(a_, b_, ob);
            }
            if (l15 < 2) {
                int row = wr * 128 + m * 16 + g4 * 4 + q;
                int slot = wc * 4 + l15 * 2;
                cand[row * 17 + slot] = a_;
                cand[row * 17 + slot + 1] = b_;
            }
        }
    __syncthreads();
    if (tid < 256) {
        unsigned best = cand[tid * 17], second = cand[tid * 17 + 1];
#pragma unroll
        for (int i = 2; i < 16; i += 2) {
            top2u(best, second, cand[tid * 17 + i]);
            top2u(best, second, cand[tid * 17 + i + 1]);
        }
        size_t o = (size_t)(rowBase + tid) * 64 + cb * 2;   // [row][cb][2]
        pv[o] = best;
        pv[o + 1] = second;
    }
}

// ---------- combine + gather: exact re-rank, quantize/diff; partial diff per block ----
__global__ __launch_bounds__(256) void k_combine(
    const unsigned* __restrict__ pv, const float* __restrict__ f,
    const ushortT* __restrict__ EhT, const ushortT* __restrict__ ElT,
    const float* __restrict__ pc,
    int* __restrict__ indws, float* __restrict__ o_ind, float* __restrict__ counts,
    float* __restrict__ o_q, float* __restrict__ diffp) {
    __shared__ float dsum[4];
    int w = threadIdx.x >> 6, l = threadIdx.x & 63;
    int row = blockIdx.x * 4 + w;
    unsigned e = pv[(size_t)row * 64 + l];   // coalesced 256B per row
    unsigned mn = e;
#pragma unroll
    for (int m = 1; m < 64; m <<= 1) {
        unsigned o = __shfl_xor((int)mn, m);
        mn = o < mn ? o : mn;
    }
    // +2.0 = 1.0 pack-truncation + 1.0 (14-sigma bf16 screening error)
    float thr = unpackD(mn) + 2.0f;
    float dl = unpackD(e);
    float bestd = 3.4e38f; int bestj = 0x7fffffff;
    float4 fa = *(const float4*)&f[(size_t)row * K + l * 8];
    float4 fb = *(const float4*)&f[(size_t)row * K + l * 8 + 4];
    float fx[8] = {fa.x, fa.y, fa.z, fa.w, fb.x, fb.y, fb.z, fb.w};
    s8v qh, ql;                         // kept fragments of the winning code row
    unsigned long long mask = __ballot(dl <= thr);
    while (mask) {
        int b = __ffsll(mask) - 1;
        mask &= mask - 1;
        int j = (int)(__shfl((int)e, b) & 0x1fff);
        s8v hv = *(const s8v*)(EhT + (size_t)j * K + l * 8);
        s8v lv = *(const s8v*)(ElT + (size_t)j * K + l * 8);
        float a = 0.f;
#pragma unroll
        for (int q = 0; q < 8; ++q)
            a = fmaf(fx[q], bf2f((ushortT)hv[q]) + bf2f((ushortT)lv[q]), a);
#pragma unroll
        for (int m = 1; m < 64; m <<= 1) a += __shfl_xor(a, m);
        float cj = 0.f;
#pragma unroll
        for (int kb = 0; kb < 8; ++kb) cj += pc[(size_t)kb * M + j];
        float d = cj - 2.f * a;
        if (d < bestd || (d == bestd && j < bestj)) {
            bestd = d; bestj = j; qh = hv; ql = lv;
        }
    }
    // fused gather: quantize_st = x + (q - x), diff partial = (q - x)^2
    float os[8];
    float local = 0.f;
#pragma unroll
    for (int q = 0; q < 8; ++q) {
        float qv = bf2f((ushortT)qh[q]) + bf2f((ushortT)ql[q]);
        float d = qv - fx[q];
        os[q] = fx[q] + d;
        local = fmaf(d, d, local);
    }
    float4 o0 = {os[0], os[1], os[2], os[3]};
    float4 o1 = {os[4], os[5], os[6], os[7]};
    *(float4*)&o_q[(size_t)row * K + l * 8] = o0;
    *(float4*)&o_q[(size_t)row * K + l * 8 + 4] = o1;
#pragma unroll
    for (int m = 1; m < 64; m <<= 1) local += __shfl_xor(local, m);
    if (l == 0) {
        indws[row] = bestj;
        o_ind[row] = (float)bestj;
        atomicAdd(&counts[bestj], 1.0f);   // scattered addresses: fine
        dsum[w] = local;
    }
    __syncthreads();
    if (threadIdx.x == 0)
        diffp[blockIdx.x] = dsum[0] + dsum[1] + dsum[2] + dsum[3];   // no atomic
}

// ---------- EMA + new_embed (blocks 0..255); o_ncs + diff finalize (block 256) ----------
__global__ __launch_bounds__(256) void k_ema(
    const float* __restrict__ f, const int* __restrict__ indws,
    const float* __restrict__ ea, float* __restrict__ o_avg, float* __restrict__ o_ne,
    const float* __restrict__ cs_in, const float* __restrict__ counts,
    float* __restrict__ o_ncs,
    const float* __restrict__ diffp, float* __restrict__ o_diff) {
    int b = blockIdx.x, t = threadIdx.x;
    __shared__ float wsum[4];
    if (b == 256) {   // o_ncs + diff finalize
        float loc = 0.f;
#pragma unroll 32
        for (int i = 0; i < 32; ++i) {
            int j = i * 256 + t;
            o_ncs[j] = 0.99f * cs_in[j] + 0.01f * counts[j];
        }
        float dl = 0.f;
#pragma unroll
        for (int i = 0; i < 8; ++i) dl += diffp[i * 256 + t];
#pragma unroll
        for (int off = 32; off; off >>= 1) dl += __shfl_down(dl, off);
        if ((t & 63) == 0) wsum[t >> 6] = dl;
        __syncthreads();
        if (t == 0)
            o_diff[0] = (wsum[0] + wsum[1] + wsum[2] + wsum[3]) * (1.0f / 4194304.0f);
        (void)loc;
        return;
    }
    __shared__ float acc[512 * 33];   // [d][c] padded, conflict-free
    __shared__ int q[8192];
    __shared__ int qn;
    __shared__ float csr_s[32];
    __shared__ float nsh;
    for (int i = t; i < 512 * 33; i += 256) acc[i] = 0.f;
    if (t == 0) qn = 0;
    __syncthreads();
    for (int r = t; r < N; r += 256) {
        int j = indws[r];
        if ((j >> 5) == b) {
            int s = atomicAdd(&qn, 1);
            q[s] = (r << 5) | (j & 31);
        }
    }
    __syncthreads();
    int nq = qn;
    int s = 0;
    for (; s + 4 <= nq; s += 4) {
        int e0 = q[s], e1 = q[s + 1], e2 = q[s + 2], e3 = q[s + 3];
        float a0 = f[(size_t)(e0 >> 5) * K + t],       c0 = f[(size_t)(e0 >> 5) * K + t + 256];
        float a1 = f[(size_t)(e1 >> 5) * K + t],       c1 = f[(size_t)(e1 >> 5) * K + t + 256];
        float a2 = f[(size_t)(e2 >> 5) * K + t],       c2 = f[(size_t)(e2 >> 5) * K + t + 256];
        float a3 = f[(size_t)(e3 >> 5) * K + t],       c3 = f[(size_t)(e3 >> 5) * K + t + 256];
        acc[t * 33 + (e0 & 31)] += a0;         acc[(t + 256) * 33 + (e0 & 31)] += c0;
        acc[t * 33 + (e1 & 31)] += a1;         acc[(t + 256) * 33 + (e1 & 31)] += c1;
        acc[t * 33 + (e2 & 31)] += a2;         acc[(t + 256) * 33 + (e2 & 31)] += c2;
        acc[t * 33 + (e3 & 31)] += a3;         acc[(t + 256) * 33 + (e3 & 31)] += c3;
    }
    for (; s < nq; ++s) {
        int e = q[s];
        float a0 = f[(size_t)(e >> 5) * K + t];
        float c0 = f[(size_t)(e >> 5) * K + t + 256];
        acc[t * 33 + (e & 31)] += a0;
        acc[(t + 256) * 33 + (e & 31)] += c0;
    }
    // local n reduction (identical fixed order in every block -> deterministic)
    float loc = 0.f;
#pragma unroll 32
    for (int i = 0; i < 32; ++i) {
        int j = i * 256 + t;
        loc += 0.99f * cs_in[j] + 0.01f * counts[j];
    }
#pragma unroll
    for (int off = 32; off; off >>= 1) loc += __shfl_down(loc, off);
    __syncthreads();
    if ((t & 63) == 0) wsum[t >> 6] = loc;
    __syncthreads();
    if (t == 0) nsh = wsum[0] + wsum[1] + wsum[2] + wsum[3];
    __syncthreads();
    if (t < 32) {
        int j = b * 32 + t;
        float v = 0.99f * cs_in[j] + 0.01f * counts[j];
        float n = nsh;
        csr_s[t] = (v + 1e-5f) / (n + 8192.0f * 1e-5f) * n;
    }
    __syncthreads();
    for (int i = t; i < 512 * 32; i += 256) {
        int d = i >> 5, c = i & 31;
        size_t o = (size_t)d * M + b * 32 + c;
        float val = 0.99f * ea[o] + 0.01f * acc[d * 33 + c];
        o_avg[o] = val;
        o_ne[o] = val / csr_s[c];
    }
}

extern "C" void kernel_launch(void* const* d_in, const int* in_sizes, int n_in,
                              void* d_out, int out_size, void* d_ws, size_t ws_size,
                              hipStream_t stream) {
    const float* f     = (const float*)d_in[0];
    const float* E     = (const float*)d_in[1];
    const float* cs_in = (const float*)d_in[2];
    const float* ea    = (const float*)d_in[3];

    float* out = (float*)d_out;
    float* o_q    = out;                   // 4194304
    float* o_diff = out + 4194304;         // 1
    float* o_ind  = out + 4194305;         // 8192
    float* o_ne   = out + 4202497;         // 4194304
    float* o_ncs  = out + 8396801;         // 8192
    float* o_avg  = out + 8404993;         // 4194304

    // overlays (lifetimes audited):
    //   o_q  region: Fh (8 MB) — read by k_score only; k_combine writes o_q after
    //   o_ne region: EhT,ElT (16 MB) — read by score/combine; k_ema writes o_ne after
    //   o_avg region: pv (2 MB u32) — dead after k_combine; k_ema writes o_avg after
    ushortT* Fh  = (ushortT*)o_q;
    ushortT* EhT = (ushortT*)o_ne;
    ushortT* ElT = EhT + (size_t)M * K;
    unsigned* pv = (unsigned*)o_avg;       // [8192 rows][32 cb][2] u32

    float* wsf    = (float*)d_ws;
    float* counts = wsf + 8192;            // 8192
    int*   indws  = (int*)(wsf + 24576);   // 8192
    float* diffp  = wsf + 32768;           // 2048 per-block diff partials
    float* pc     = wsf + 40960;           // [8][8192] norm partials

    k_prep   <<<3072, 256, 0, stream>>>(f, E, Fh, EhT, ElT, pc, counts);
    k_score  <<<1024, 512, 0, stream>>>(Fh, EhT, pc, pv);
    k_combine<<<2048, 256, 0, stream>>>(pv, f, EhT, ElT, pc, indws, o_ind, counts,
                                        o_q, diffp);                  // frees Fh
    k_ema    <<<257, 256, 0, stream>>>(f, indws, ea, o_avg, o_ne,
                                       cs_in, counts, o_ncs,
                                       diffp, o_diff);                // frees pv, EhT/ElT
}